// Round 3
// baseline (265.495 us; speedup 1.0000x reference)
//
#include <hip/hip_runtime.h>
#include <hip/hip_fp16.h>

#define DIM 128
#define EPS 1e-5f
#define WPB 4            // waves per block
#define UF  4            // 4 edges per quarter-wave per trip -> 16 edges/trip
#define PERSIST_BLOCKS 2048   // 8192 waves = 256 CU x 32 waves (HW cap)

// native clang ext-vectors (needed for __builtin_nontemporal_store)
typedef float vfloat2 __attribute__((ext_vector_type(2)));

// ---------------------------------------------------------------------------
// Prep kernel (fused): convert x fp32 -> fp16; build CSR row_ptr from the
// sorted edge_row (thread e covers rows (row[e-1], row[e]]).
// ---------------------------------------------------------------------------
__global__ void prep_kernel(const float4* __restrict__ x4,
                            __half2* __restrict__ xh2,
                            const int* __restrict__ edge_row,
                            int* __restrict__ row_ptr,
                            int n4, int n_nodes, int n_edges)
{
    int i = blockIdx.x * blockDim.x + threadIdx.x;
    if (i < n4) {
        float4 v = x4[i];
        xh2[2 * i]     = __float22half2_rn(make_float2(v.x, v.y));
        xh2[2 * i + 1] = __float22half2_rn(make_float2(v.z, v.w));
    }
    if (i < n_edges) {
        int cur  = edge_row[i];
        int prev = (i == 0) ? -1 : edge_row[i - 1];
        for (int r = prev + 1; r <= cur; ++r) row_ptr[r] = i;
        if (i == n_edges - 1) {
            for (int r = cur + 1; r <= n_nodes; ++r) row_ptr[r] = n_edges;
        }
    }
}

// ---------------------------------------------------------------------------
// Main kernel: persistent waves. Each wave owns a CONTIGUOUS chunk of nodes:
//   - occupancy pinned at the 32-waves/CU cap for the whole kernel
//     (R1/R2 lesson: TLP, not per-wave ILP, hides the gather latency here)
//   - edge-array reads are sequential across a wave's nodes
//   - node n+1's row_ptr start == node n's end -> one scalar load per node,
//     issued at loop top where it hides under the residual/edge loads
// Inner loop is the proven R0 geometry: one wave per node, quarter-wave owns
// 4 edges/trip, sub=lane&15 owns dim group [sub*8, sub*8+8) gathered as 16B.
// Masked edges: c -> 0 (hot row 0; R1 showed unmasked c costs +54MB FETCH).
// ---------------------------------------------------------------------------
__global__ __launch_bounds__(WPB * 64)
void gnn_fused_kernel(const uint4* __restrict__ xh16,   // fp16 x, 16B units
                      const int*   __restrict__ row_ptr,
                      const int*   __restrict__ edge_col,
                      const float* __restrict__ edge_val,
                      const float* __restrict__ gamma,
                      const float* __restrict__ beta,
                      float*       __restrict__ out,
                      int n_nodes, int n_edges)
{
    const int wave = threadIdx.x >> 6;
    const int lane = threadIdx.x & 63;
    const int q    = lane >> 4;                 // quarter: 4 edges/trip
    const int sub  = lane & 15;                 // dim group [sub*8, sub*8+8)

    const int total_waves = gridDim.x * WPB;
    const int wid = blockIdx.x * WPB + wave;
    const int npw = (n_nodes + total_waves - 1) / total_waves;
    const int n0  = wid * npw;
    const int n1  = min(n0 + npw, n_nodes);
    if (n0 >= n1) return;

    const int emax = n_edges - 4;

    // loop-invariant epilogue constants (per lane)
    const int didx = sub * 4 + q;
    const float2 g = ((const float2*)gamma)[didx];
    const float2 b = ((const float2*)beta)[didx];

    int start = row_ptr[n0];
    for (int node = n0; node < n1; ++node) {
        const int end = row_ptr[node + 1];      // only new CSR load per node
        const unsigned len = (unsigned)(end - start);

        // residual row: issue early, latency hides under the edge loop
        const uint4 xv = xh16[node * (DIM / 8) + sub];

        float acc[8];
#pragma unroll
        for (int k = 0; k < 8; ++k) acc[k] = 0.f;

        const int ebase = start & ~3;           // 16B-align edge vec loads
        for (int e0 = ebase; e0 < end; e0 += 4 * UF) {
            const int b0 = e0 + 4 * q;          // this quarter's 4 edges
            const int bc = min(b0, emax);       // clamp: stay in-array
            int4   c4 = *(const int4*)  (edge_col + bc);
            float4 w4 = *(const float4*)(edge_val + bc);

            int   c[UF] = {c4.x, c4.y, c4.z, c4.w};
            float w[UF] = {w4.x, w4.y, w4.z, w4.w};

            const int off = b0 - start;         // may be <0 at head (q=0)
#pragma unroll
            for (int u = 0; u < UF; ++u) {
                bool in = (unsigned)(off + u) < len;
                c[u] = in ? c[u] : 0;           // masked -> hot row 0
                w[u] = in ? w[u] : 0.f;
            }

            uint4 v[UF];
#pragma unroll
            for (int u = 0; u < UF; ++u)
                v[u] = xh16[c[u] * (DIM / 8) + sub];  // 16B/lane gather

#pragma unroll
            for (int u = 0; u < UF; ++u) {
                const __half* hp = (const __half*)&v[u];
#pragma unroll
                for (int j = 0; j < 8; ++j)     // fp16 operand -> v_fma_mix
                    acc[j] = fmaf(w[u], __half2float(hp[j]), acc[j]);
            }
        }

        // fold the 4 quarter-waves (disjoint edge subsets) into every lane
#pragma unroll
        for (int k = 0; k < 8; ++k) {
            acc[k] += __shfl_xor(acc[k], 16, 64);
            acc[k] += __shfl_xor(acc[k], 32, 64);
        }

        // residual from fp16 x
        const __half* xp = (const __half*)&xv;
        float h[8];
#pragma unroll
        for (int j = 0; j < 8; ++j) h[j] = acc[j] + __half2float(xp[j]);

        // layernorm stats: per-lane over 8 dims, butterfly over sub (1,2,4,8)
        float s = 0.f, sq = 0.f;
#pragma unroll
        for (int k = 0; k < 8; ++k) { s += h[k]; sq += h[k] * h[k]; }
#pragma unroll
        for (int off = 1; off <= 8; off <<= 1) {
            s  += __shfl_xor(s,  off, 64);
            sq += __shfl_xor(sq, off, 64);
        }
        const float mean = s * (1.0f / (float)DIM);
        const float var  = sq * (1.0f / (float)DIM) - mean * mean;
        const float rs   = rsqrtf(var + EPS);

        // lane (q,sub) writes dims sub*8 + 2q + {0,1} (512B/node contiguous)
        float hx = (q < 2) ? ((q == 0) ? h[0] : h[2]) : ((q == 2) ? h[4] : h[6]);
        float hy = (q < 2) ? ((q == 0) ? h[1] : h[3]) : ((q == 2) ? h[5] : h[7]);
        vfloat2 o;
        o.x = (hx - mean) * rs * g.x + b.x;
        o.y = (hy - mean) * rs * g.y + b.y;
        __builtin_nontemporal_store(o, (vfloat2*)out + node * (DIM / 2) + didx);

        start = end;                            // CSR chain: no reload
    }
}

extern "C" void kernel_launch(void* const* d_in, const int* in_sizes, int n_in,
                              void* d_out, int out_size, void* d_ws, size_t ws_size,
                              hipStream_t stream)
{
    const float* x        = (const float*)d_in[0];
    const int*   edge_row = (const int*)  d_in[1];
    const int*   edge_col = (const int*)  d_in[2];
    const float* edge_val = (const float*)d_in[3];
    const float* gamma    = (const float*)d_in[4];
    const float* beta     = (const float*)d_in[5];
    float*       out      = (float*)d_out;

    const int n_nodes = in_sizes[0] / DIM;   // 100000
    const int n_edges = in_sizes[1];         // 3200000
    const int n_elem  = in_sizes[0];         // N*DIM
    const int n4      = n_elem / 4;

    // workspace: [x_half: n_elem*2 B][row_ptr: (n_nodes+1)*4 B]
    __half2* xh2     = (__half2*)d_ws;
    int*     row_ptr = (int*)((char*)d_ws + (size_t)n_elem * sizeof(__half));

    int prep_threads = (n4 > n_edges) ? n4 : n_edges;
    prep_kernel<<<(prep_threads + 255) / 256, 256, 0, stream>>>(
        (const float4*)x, xh2, edge_row, row_ptr, n4, n_nodes, n_edges);

    int blocks = (n_nodes + WPB - 1) / WPB;
    if (blocks > PERSIST_BLOCKS) blocks = PERSIST_BLOCKS;
    gnn_fused_kernel<<<blocks, WPB * 64, 0, stream>>>(
        (const uint4*)d_ws, row_ptr, edge_col, edge_val, gamma, beta, out,
        n_nodes, n_edges);
}

// Round 5
// 219.555 us; speedup vs baseline: 1.2092x; 1.2092x over previous
//
#include <hip/hip_runtime.h>
#include <hip/hip_fp16.h>

#define DIM 128
#define EPS 1e-5f
#define WPB 4            // waves per block
#define UF  4            // 4 edges per quarter-wave per trip -> 16 edges/trip

// native clang ext-vectors (needed for __builtin_nontemporal_store)
typedef float vfloat2 __attribute__((ext_vector_type(2)));

// ---------------------------------------------------------------------------
// Prep 1: per-row symmetric int8 quantization of x.
// 32 threads per row (4 elems/thread). Row absmax via half-wave shfl_xor
// reduce (offsets 1..16 keep each aligned 32-thread group closed).
// Stored BIASED: u = rint(x*127/rowmax) + 128 in [1,255]; scale = rowmax/127.
// Error model: per-term rms = scale/sqrt(12) ~ 0.008 (vs fp8's ~0.027, whose
// 0.16 absmax failed R4); predicted output absmax ~ 0.05.
// ---------------------------------------------------------------------------
__global__ void quant_kernel(const float4* __restrict__ x4,
                             unsigned int* __restrict__ x8,
                             float*        __restrict__ scales,
                             int n_nodes)
{
    const int t   = blockIdx.x * blockDim.x + threadIdx.x;
    const int row = t >> 5;                    // 32 threads per row
    if (row >= n_nodes) return;

    const float4 v = x4[t];
    float m = fmaxf(fmaxf(fabsf(v.x), fabsf(v.y)),
                    fmaxf(fabsf(v.z), fabsf(v.w)));
#pragma unroll
    for (int off = 1; off <= 16; off <<= 1)
        m = fmaxf(m, __shfl_xor(m, off, 64));

    const float inv = (m > 0.f) ? 127.f / m : 0.f;
    const int q0 = __float2int_rn(v.x * inv) + 128;
    const int q1 = __float2int_rn(v.y * inv) + 128;
    const int q2 = __float2int_rn(v.z * inv) + 128;
    const int q3 = __float2int_rn(v.w * inv) + 128;
    x8[t] = (unsigned)q0 | ((unsigned)q1 << 8) |
            ((unsigned)q2 << 16) | ((unsigned)q3 << 24);

    if ((threadIdx.x & 31) == 0)
        scales[row] = m * (1.f / 127.f);
}

// ---------------------------------------------------------------------------
// Prep 2: build CSR row_ptr from the sorted edge_row.
// ---------------------------------------------------------------------------
__global__ void csr_kernel(const int* __restrict__ edge_row,
                           int* __restrict__ row_ptr,
                           int n_nodes, int n_edges)
{
    int i = blockIdx.x * blockDim.x + threadIdx.x;
    if (i >= n_edges) return;
    int cur  = edge_row[i];
    int prev = (i == 0) ? -1 : edge_row[i - 1];
    for (int r = prev + 1; r <= cur; ++r) row_ptr[r] = i;
    if (i == n_edges - 1) {
        for (int r = cur + 1; r <= n_nodes; ++r) row_ptr[r] = n_edges;
    }
}

// ---------------------------------------------------------------------------
// Main kernel: EXACT R0 geometry (proven best: short waves, high churn, max
// MLP on the ~4 TB/s random-fill path). One wave per node; quarter-wave q
// owns 4 edges/trip; sub=lane&15 owns dims [sub*8, sub*8+8).
// Change vs R0: x gathered as int8 (8B/lane, 128B/row -> halves gather bytes
// and doubles effective L2 row capacity). Decode: v_cvt_f32_ubyte (biased),
// bias folded out via one running Kws per lane (dim-uniform correction).
// Residual from original fp32 x (exact). Masked edges: c -> 0 (hot row 0;
// R1 showed unmasked c costs +54MB FETCH), w -> 0 (kills ws and Kws terms).
// ---------------------------------------------------------------------------
__global__ __launch_bounds__(WPB * 64)
void gnn_fused_kernel(const uint2* __restrict__ x8,     // int8 x, 8B units
                      const float4* __restrict__ xf,    // fp32 x, 16B units
                      const float* __restrict__ scales, // rowmax/127
                      const int*   __restrict__ row_ptr,
                      const int*   __restrict__ edge_col,
                      const float* __restrict__ edge_val,
                      const float* __restrict__ gamma,
                      const float* __restrict__ beta,
                      float*       __restrict__ out,
                      int n_nodes, int n_edges)
{
    const int wave = threadIdx.x >> 6;
    const int lane = threadIdx.x & 63;
    const int q    = lane >> 4;                 // quarter: 4 edges/trip
    const int sub  = lane & 15;                 // dim group [sub*8, sub*8+8)
    const int node = blockIdx.x * WPB + wave;
    if (node >= n_nodes) return;

    const int start = row_ptr[node];
    const int end   = row_ptr[node + 1];
    const unsigned len = (unsigned)(end - start);

    // fp32 residual row (exact): 2x16B per lane, issued before the edge loop
    const float4 xr0 = xf[node * (DIM / 4) + sub * 2];
    const float4 xr1 = xf[node * (DIM / 4) + sub * 2 + 1];

    float acc[8];
#pragma unroll
    for (int k = 0; k < 8; ++k) acc[k] = 0.f;
    float Kws = 0.f;                            // running sum of ws (bias fold)

    const int ebase = start & ~3;               // 16B-align edge vec loads
    const int emax  = n_edges - 4;
    for (int e0 = ebase; e0 < end; e0 += 4 * UF) {
        const int b0 = e0 + 4 * q;              // this quarter's 4 edges
        const int bc = min(b0, emax);           // clamp: stay in-array
        int4   c4 = *(const int4*)  (edge_col + bc);
        float4 w4 = *(const float4*)(edge_val + bc);

        int   c[UF] = {c4.x, c4.y, c4.z, c4.w};
        float w[UF] = {w4.x, w4.y, w4.z, w4.w};

        const int off = b0 - start;             // may be <0 at head (q=0)
#pragma unroll
        for (int u = 0; u < UF; ++u) {
            bool in = (unsigned)(off + u) < len;
            c[u] = in ? c[u] : 0;               // masked -> hot row 0
            w[u] = in ? w[u] : 0.f;
        }

        // per-edge scale (400KB array, L2-hot; 16 duplicate lanes coalesce)
        float ws[UF];
#pragma unroll
        for (int u = 0; u < UF; ++u)
            ws[u] = w[u] * scales[c[u]];

        uint2 v[UF];
#pragma unroll
        for (int u = 0; u < UF; ++u)
            v[u] = x8[c[u] * (DIM / 8) + sub];  // 8B/lane gather, 128B/row

#pragma unroll
        for (int u = 0; u < UF; ++u) {
            const unsigned lo = v[u].x, hi = v[u].y;
            Kws += ws[u];
            // (float)(byte extract) -> v_cvt_f32_ubyteN (1 instr each)
            acc[0] = fmaf(ws[u], (float)( lo        & 0xffu), acc[0]);
            acc[1] = fmaf(ws[u], (float)((lo >>  8) & 0xffu), acc[1]);
            acc[2] = fmaf(ws[u], (float)((lo >> 16) & 0xffu), acc[2]);
            acc[3] = fmaf(ws[u], (float)( lo >> 24        ), acc[3]);
            acc[4] = fmaf(ws[u], (float)( hi        & 0xffu), acc[4]);
            acc[5] = fmaf(ws[u], (float)((hi >>  8) & 0xffu), acc[5]);
            acc[6] = fmaf(ws[u], (float)((hi >> 16) & 0xffu), acc[6]);
            acc[7] = fmaf(ws[u], (float)( hi >> 24        ), acc[7]);
        }
    }

    // fold out the +128 bias (dim-uniform): acc[j] -= 128 * sum(ws)
#pragma unroll
    for (int k = 0; k < 8; ++k)
        acc[k] = fmaf(-128.f, Kws, acc[k]);

    // fold the 4 quarter-waves (disjoint edge subsets) into every lane
#pragma unroll
    for (int k = 0; k < 8; ++k) {
        acc[k] += __shfl_xor(acc[k], 16, 64);
        acc[k] += __shfl_xor(acc[k], 32, 64);
    }

    // residual from fp32 x (exact)
    float h[8];
    h[0] = acc[0] + xr0.x;  h[1] = acc[1] + xr0.y;
    h[2] = acc[2] + xr0.z;  h[3] = acc[3] + xr0.w;
    h[4] = acc[4] + xr1.x;  h[5] = acc[5] + xr1.y;
    h[6] = acc[6] + xr1.z;  h[7] = acc[7] + xr1.w;

    // layernorm stats: per-lane over 8 dims, then butterfly over sub (1,2,4,8)
    float s = 0.f, sq = 0.f;
#pragma unroll
    for (int k = 0; k < 8; ++k) { s += h[k]; sq += h[k] * h[k]; }
#pragma unroll
    for (int off = 1; off <= 8; off <<= 1) {
        s  += __shfl_xor(s,  off, 64);
        sq += __shfl_xor(sq, off, 64);
    }
    const float mean = s * (1.0f / (float)DIM);
    const float var  = sq * (1.0f / (float)DIM) - mean * mean;
    const float rs   = rsqrtf(var + EPS);

    // lane (q,sub) writes dims sub*8 + 2q + {0,1} (512B contiguous per node)
    float hx = (q < 2) ? ((q == 0) ? h[0] : h[2]) : ((q == 2) ? h[4] : h[6]);
    float hy = (q < 2) ? ((q == 0) ? h[1] : h[3]) : ((q == 2) ? h[5] : h[7]);
    const int didx = sub * 4 + q;
    const float2 g = ((const float2*)gamma)[didx];
    const float2 b = ((const float2*)beta)[didx];
    vfloat2 o;
    o.x = (hx - mean) * rs * g.x + b.x;
    o.y = (hy - mean) * rs * g.y + b.y;
    __builtin_nontemporal_store(o, (vfloat2*)out + node * (DIM / 2) + didx);
}

extern "C" void kernel_launch(void* const* d_in, const int* in_sizes, int n_in,
                              void* d_out, int out_size, void* d_ws, size_t ws_size,
                              hipStream_t stream)
{
    const float* x        = (const float*)d_in[0];
    const int*   edge_row = (const int*)  d_in[1];
    const int*   edge_col = (const int*)  d_in[2];
    const float* edge_val = (const float*)d_in[3];
    const float* gamma    = (const float*)d_in[4];
    const float* beta     = (const float*)d_in[5];
    float*       out      = (float*)d_out;

    const int n_nodes = in_sizes[0] / DIM;   // 100000
    const int n_edges = in_sizes[1];         // 3200000
    const int n_elem  = in_sizes[0];         // N*DIM

    // workspace: [x_int8: n_elem B][row_ptr: (n_nodes+1)*4 B][scales: n_nodes*4 B]
    unsigned int* x8      = (unsigned int*)d_ws;
    int*          row_ptr = (int*)  ((char*)d_ws + (size_t)n_elem);
    float*        scales  = (float*)((char*)d_ws + (size_t)n_elem
                                     + (size_t)(n_nodes + 1) * sizeof(int));

    const int qthreads = n_nodes * (DIM / 4);   // 32 threads/row
    quant_kernel<<<(qthreads + 255) / 256, 256, 0, stream>>>(
        (const float4*)x, x8, scales, n_nodes);
    csr_kernel<<<(n_edges + 255) / 256, 256, 0, stream>>>(
        edge_row, row_ptr, n_nodes, n_edges);

    const int blocks = (n_nodes + WPB - 1) / WPB;
    gnn_fused_kernel<<<blocks, WPB * 64, 0, stream>>>(
        (const uint2*)x8, (const float4*)x, scales, row_ptr, edge_col,
        edge_val, gamma, beta, out, n_nodes, n_edges);
}